// Round 6
// baseline (978.470 us; speedup 1.0000x reference)
//
#include <hip/hip_runtime.h>
#include <hip/hip_bf16.h>

// B=2, L=4096, C=512, H=8, hd=64. f32 in/out; bf16 MFMA compute.
// v14 = v12 baseline (v13 rotation reverted: null) + DIAGNOSTIC ablation.
// Four structurally different flash kernels (v8/v10/v12/v13) all pin at
// ~250us while MfmaUtil, VALUBusy, L2 traffic (4x!), occupancy all move.
// Per-SIMD chunk slot 2364cy vs ~400cy issue + ~225cy L2 latency: the wall
// is invisible in available counters. This round measures it directly:
//   flash_attn<0>: real kernel (correct output)          ~252us expected
//   flash_attn<1>: compute-only, no in-loop VMEM, x4 work (dead output)
//   flash_attn<2>: same loop but coalesced 1KB wave-loads, x2 (dead output)
// Both ablations run AFTER the real flash, write into the then-dead q
// buffer. Headline dur_us intentionally regresses this round; the table max
// (by name) + headline sum identify both arm durations.

typedef __attribute__((ext_vector_type(8))) short short8;    // 8 bf16
typedef __attribute__((ext_vector_type(4))) short short4v;   // 4 bf16
typedef __attribute__((ext_vector_type(4))) float floatx4;   // MFMA C/D

#define MFMA(a, b, c)   __builtin_amdgcn_mfma_f32_16x16x32_bf16((a), (b), (c), 0, 0, 0)
#define MFMA16(a, b, c) __builtin_amdgcn_mfma_f32_16x16x16bf16_1k((a), (b), (c), 0, 0, 0)

__device__ __forceinline__ unsigned short f2bf(float f) {
    unsigned int u = __builtin_bit_cast(unsigned int, f);
    return (unsigned short)((u + 0x7fffu + ((u >> 16) & 1u)) >> 16);  // RTNE
}
__device__ __forceinline__ unsigned int pack2(float lo, float hi) {
    __hip_bfloat162 h = __float22bfloat162_rn(make_float2(lo, hi));  // 1 instr
    unsigned int r;
    __builtin_memcpy(&r, &h, 4);
    return r;
}

__global__ __launch_bounds__(256) void conv_bf16(
    const float* __restrict__ src, ushort* __restrict__ dst, int n8)
{
    int i = blockIdx.x * blockDim.x + threadIdx.x;
    if (i >= n8) return;
    const float4* s = (const float4*)src + (size_t)i * 2;
    float4 a = s[0], b = s[1];
    uint4 r = { pack2(a.x, a.y), pack2(a.z, a.w), pack2(b.x, b.y), pack2(b.z, b.w) };
    *(uint4*)(dst + (size_t)i * 8) = r;
}

// RoPE LUT: lut[pos*32+j] = {cos, sin}(pos * 10000^(-j/32))
__global__ __launch_bounds__(256) void build_rope(float2* __restrict__ lut) {
    int i = blockIdx.x * 256 + threadIdx.x;   // 131072 entries
    int pos = i >> 5, j = i & 31;
    float invf = exp2f(-0.41524101186f * (float)j);
    float s, c;
    sincosf((float)pos * invf, &s, &c);
    lut[i] = make_float2(c, s);
}

// ---------------------------------------------------------------------------
// qkv = xb @ wb.T + b for G heads from h0; RoPE q,k (LUT); q pre-scaled by
// 0.125*log2e (flash uses exp2); v transposed (hd, L) via LDS tile, stored
// with keys PERMUTED within each 32-key chunk: position g*8 + t*4 + e holds
// key t*16 + g*4 + e  (g=quad group). Wave tile 32(M) x 64(N), block M=128.
// ---------------------------------------------------------------------------
__global__ __launch_bounds__(256) void qkv_rope(
    const ushort* __restrict__ xb,    // (8192, 512) bf16
    const ushort* __restrict__ wb,    // (1536, 512) bf16
    const float* __restrict__ bias,   // (1536,) f32
    const float2* __restrict__ lut,   // (4096, 32)
    ushort* __restrict__ q, ushort* __restrict__ k, ushort* __restrict__ vt,
    int G, int h0)
{
    __shared__ __align__(16) ushort vtile[64][136];   // 17408 B (sec==2 only)
    const int w_id = threadIdx.x >> 6;
    const int lane = threadIdx.x & 63;
    const int lr = lane & 15, quad = lane >> 4;
    const int m0 = blockIdx.x * 128 + w_id * 32;
    const int sec = blockIdx.y / G, hl = blockIdx.y % G;
    const int wc0 = sec * 512 + (h0 + hl) * 64;

    floatx4 acc[2][4] = {};
    const ushort* xrow0 = xb + (size_t)(m0 + lr) * 512 + quad * 8;
    const ushort* xrow1 = xb + (size_t)(m0 + 16 + lr) * 512 + quad * 8;
    for (int kk = 0; kk < 512; kk += 32) {
        short8 a0 = *(const short8*)(xrow0 + kk);
        short8 a1 = *(const short8*)(xrow1 + kk);
#pragma unroll
        for (int nt = 0; nt < 4; ++nt) {
            short8 b = *(const short8*)(wb + (size_t)(wc0 + nt * 16 + lr) * 512 + kk + quad * 8);
            acc[0][nt] = MFMA(a0, b, acc[0][nt]);
            acc[1][nt] = MFMA(a1, b, acc[1][nt]);
        }
    }

    if (sec < 2) {
#pragma unroll
        for (int mt = 0; mt < 2; ++mt)
#pragma unroll
            for (int nt = 0; nt < 4; ++nt) {
                const int d = nt * 16 + lr;
                const float bv = bias[wc0 + d];
#pragma unroll
                for (int r = 0; r < 4; ++r) {
                    const int row = m0 + mt * 16 + quad * 4 + r;
                    const int b_ = row >> 12;
                    const int pos = row & 4095;
                    float val = acc[mt][nt][r] + bv;
                    const size_t bhl = (size_t)(b_ * G + hl);
                    float partner = __shfl_xor(val, 1);
                    float2 cs = lut[(pos << 5) | (d & 31)];
                    float rh = (d & 1) ? partner : -partner;   // rotate_half
                    float rv = val * cs.x + rh * cs.y;
                    if (sec == 0) rv *= 0.18033688011112042f;  // 0.125*log2(e)
                    ushort* dst = (sec == 0) ? q : k;
                    dst[(bhl * 4096 + pos) * 64 + d] = f2bf(rv);
                }
            }
    } else {
        // v: stage bf16 tile (64 d x 128 pos) in LDS, store permuted + 16B.
#pragma unroll
        for (int mt = 0; mt < 2; ++mt)
#pragma unroll
            for (int nt = 0; nt < 4; ++nt) {
                const int d = nt * 16 + lr;
                const float bv = bias[wc0 + d];
                short4v v4;
#pragma unroll
                for (int r = 0; r < 4; ++r)
                    v4[r] = (short)f2bf(acc[mt][nt][r] + bv);
                *(short4v*)&vtile[d][w_id * 32 + mt * 16 + quad * 4] = v4;
            }
        __syncthreads();
        const int m0b = blockIdx.x * 128;
        const int bb = m0b >> 12;
        const int pos0 = m0b & 4095;
        const size_t bhl = (size_t)(bb * G + hl);
        const int tid = threadIdx.x;
#pragma unroll
        for (int i = 0; i < 4; ++i) {
            const int d = i * 16 + (tid >> 4);
            const int pp = (tid & 15) * 8;      // store position in tile
            const int cb = pp & ~31;            // 32-key chunk base
            const int g  = (pp >> 3) & 3;       // quad group
            short4v a = *(const short4v*)&vtile[d][cb + g * 4];        // t=0
            short4v b = *(const short4v*)&vtile[d][cb + 16 + g * 4];   // t=1
            short8 vv = __builtin_shufflevector(a, b, 0, 1, 2, 3, 4, 5, 6, 7);
            *(short8*)(vt + (bhl * 64 + d) * 4096 + pos0 + pp) = vv;
        }
    }
}

// ---------------------------------------------------------------------------
// Flash. Block = 4 waves = 4 kh-quarters of ONE 32-query group; each wave
// covers 1024 keys in 32-key chunks, no-max softmax (exp2; log2e folded
// into q). VARIANT 0: real. VARIANT 1: compute-only (load once, 128 chunk
// bodies, no in-loop VMEM). VARIANT 2: same loop/load-count but ideal
// coalesced 1KB wave-loads, 2 passes. 1/2 write garbage to a dead buffer.
// ---------------------------------------------------------------------------
template<int VARIANT>
__global__ __launch_bounds__(256, 3) void flash_attn(
    const ushort* __restrict__ q, const ushort* __restrict__ k,
    const ushort* __restrict__ vt, ushort* __restrict__ o,
    int G, int h0)
{
    __shared__ __align__(16) float mb[65][33];   // 8580 B merge buffer
    const int kh = threadIdx.x >> 6;             // wave = kh quarter
    const int lane = threadIdx.x & 63;
    const int lr = lane & 15, quad = lane >> 4;
    const int nbh = 2 * G;
    const int bhl = blockIdx.x % nbh;
    const int qtile = blockIdx.x / nbh;
    const int b_ = bhl / G, hl = bhl % G;
    const int q0 = qtile * 32;

    const ushort* qp = q + (size_t)bhl * 262144;
    const ushort* kp = k + (size_t)bhl * 262144;
    const ushort* vp = vt + (size_t)bhl * 262144;
    ushort* op = o + (size_t)b_ * 4096 * 512 + (size_t)(h0 + hl) * 64;

    // Q^T B-frags (q pre-scaled 0.125*log2e): qf[nn][c] = B[k=32c..][n=16nn+lr]
    short8 qf[2][2];
#pragma unroll
    for (int nn = 0; nn < 2; ++nn) {
        const ushort* qb = qp + (size_t)(q0 + 16 * nn + lr) * 64 + quad * 8;
        qf[nn][0] = *(const short8*)qb;
        qf[nn][1] = *(const short8*)(qb + 32);
    }

    floatx4 oacc[4][2] = {};   // [d-tile][n-tile]
    float lsum[2] = {0.f, 0.f};
    short8 ka0[2][2], ka1[2][2];
    short8 va[4];              // [d-tile]: low 4 = t0 frag, high 4 = t1 frag
    const int kbase = kh * 1024;

    // 32-bit element offsets from uniform bases (saddr-form loads)
    const int ko = (kbase + lr) * 64 + quad * 8;   // + c*2048 + t*1024 (+32)
    const int vo = lr * 4096 + kbase + quad * 8;   // + dt*65536 + c*32

    auto ldK = [&](int c, short8 (&ka)[2][2]) {
        const ushort* kb = kp + ko + c * 2048;
#pragma unroll
        for (int t = 0; t < 2; ++t) {
            ka[t][0] = *(const short8*)(kb + t * 1024);
            ka[t][1] = *(const short8*)(kb + t * 1024 + 32);
        }
    };
    auto ldV = [&](int c) {
        const ushort* vb = vp + vo + c * 32;
#pragma unroll
        for (int dt = 0; dt < 4; ++dt)
            va[dt] = *(const short8*)(vb + dt * 65536);
    };
    // Ablation loads: identical count/width, ideal coalescing (1KB/instr).
    auto ldKc = [&](int c, short8 (&ka)[2][2]) {
        const ushort* kb = kp + (c & 31) * 2048 + lane * 8;
        ka[0][0] = *(const short8*)(kb);
        ka[0][1] = *(const short8*)(kb + 512);
        ka[1][0] = *(const short8*)(kb + 1024);
        ka[1][1] = *(const short8*)(kb + 1536);
    };
    auto ldVc = [&](int c) {
        const ushort* vb = vp + (c & 31) * 2048 + lane * 8;
#pragma unroll
        for (int dt = 0; dt < 4; ++dt)
            va[dt] = *(const short8*)(vb + dt * 512);
    };
    auto process = [&](short8 (&ka)[2][2]) {
#pragma unroll
        for (int t = 0; t < 2; ++t) {
#pragma unroll
            for (int nn = 0; nn < 2; ++nn) {
                floatx4 s = {};
                s = MFMA(ka[t][0], qf[nn][0], s);
                s = MFMA(ka[t][1], qf[nn][1], s);
                float p0 = exp2f(s[0]), p1 = exp2f(s[1]);
                float p2 = exp2f(s[2]), p3 = exp2f(s[3]);
                lsum[nn] += (p0 + p1) + (p2 + p3);
                uint2 u = { pack2(p0, p1), pack2(p2, p3) };
                short4v pf = __builtin_bit_cast(short4v, u);
#pragma unroll
                for (int dt = 0; dt < 4; ++dt) {
                    short4v vf = (t == 0)
                        ? __builtin_shufflevector(va[dt], va[dt], 0, 1, 2, 3)
                        : __builtin_shufflevector(va[dt], va[dt], 4, 5, 6, 7);
                    oacc[dt][nn] = MFMA16(vf, pf, oacc[dt][nn]);
                }
            }
        }
    };

    if constexpr (VARIANT == 0) {
        ldK(0, ka0);
        for (int it = 0; it < 30; it += 2) {
            ldV(it);
            ldK(it + 1, ka1);
            process(ka0);
            ldV(it + 1);
            ldK(it + 2, ka0);
            process(ka1);
        }
        ldV(30); ldK(31, ka1); process(ka0);   // chunk 30
        ldV(31); process(ka1);                 // chunk 31
    } else if constexpr (VARIANT == 1) {
        // compute-only ceiling: no in-loop VMEM, 4x chunk count
        ldK(0, ka0); ldV(0);
        for (int it = 0; it < 128; ++it)
            process(ka0);
    } else {
        // coalesced-VMEM: same load count/width, ideal pattern, 2x passes
        for (int pass = 0; pass < 2; ++pass) {
            ldKc(0, ka0);
            for (int it = 0; it < 30; it += 2) {
                ldVc(it);
                ldKc(it + 1, ka1);
                process(ka0);
                ldVc(it + 1);
                ldKc(it + 2, ka0);
                process(ka1);
            }
            ldVc(30); ldKc(31, ka1); process(ka0);
            ldVc(31); process(ka1);
        }
    }

    // l across quads (queries in lr; quads hold disjoint keys)
    lsum[0] += __shfl_xor(lsum[0], 16); lsum[0] += __shfl_xor(lsum[0], 32);
    lsum[1] += __shfl_xor(lsum[1], 16); lsum[1] += __shfl_xor(lsum[1], 32);

    // 4-way serial merge: kh=3 writes, kh=2,1 accumulate, kh=0 finalizes.
    __syncthreads();
    if (kh == 3) {
#pragma unroll
        for (int dt = 0; dt < 4; ++dt)
#pragma unroll
            for (int nn = 0; nn < 2; ++nn)
#pragma unroll
                for (int r = 0; r < 4; ++r)
                    mb[16 * dt + 4 * quad + r][16 * nn + lr] = oacc[dt][nn][r];
        if (quad == 0) {
            mb[64][lr] = lsum[0];
            mb[64][16 + lr] = lsum[1];
        }
    }
    __syncthreads();
    if (kh == 2) {
#pragma unroll
        for (int dt = 0; dt < 4; ++dt)
#pragma unroll
            for (int nn = 0; nn < 2; ++nn)
#pragma unroll
                for (int r = 0; r < 4; ++r)
                    mb[16 * dt + 4 * quad + r][16 * nn + lr] += oacc[dt][nn][r];
        if (quad == 0) {
            mb[64][lr] += lsum[0];
            mb[64][16 + lr] += lsum[1];
        }
    }
    __syncthreads();
    if (kh == 1) {
#pragma unroll
        for (int dt = 0; dt < 4; ++dt)
#pragma unroll
            for (int nn = 0; nn < 2; ++nn)
#pragma unroll
                for (int r = 0; r < 4; ++r)
                    mb[16 * dt + 4 * quad + r][16 * nn + lr] += oacc[dt][nn][r];
        if (quad == 0) {
            mb[64][lr] += lsum[0];
            mb[64][16 + lr] += lsum[1];
        }
    }
    __syncthreads();
    if (kh == 0) {
        float inv0 = 1.0f / (lsum[0] + mb[64][lr]);
        float inv1 = 1.0f / (lsum[1] + mb[64][16 + lr]);
#pragma unroll
        for (int dt = 0; dt < 4; ++dt)
#pragma unroll
            for (int nn = 0; nn < 2; ++nn) {
                float inv = nn ? inv1 : inv0;
                float v0 = (oacc[dt][nn][0] + mb[16 * dt + 4 * quad + 0][16 * nn + lr]) * inv;
                float v1 = (oacc[dt][nn][1] + mb[16 * dt + 4 * quad + 1][16 * nn + lr]) * inv;
                float v2 = (oacc[dt][nn][2] + mb[16 * dt + 4 * quad + 2][16 * nn + lr]) * inv;
                float v3 = (oacc[dt][nn][3] + mb[16 * dt + 4 * quad + 3][16 * nn + lr]) * inv;
                uint2 u = { pack2(v0, v1), pack2(v2, v3) };
                *(uint2*)(op + (size_t)(q0 + 16 * nn + lr) * 512 + 16 * dt + 4 * quad) = u;
            }
    }
}

// ---------------------------------------------------------------------------
// out(f32) = o(bf16) @ wb.T + proj_b. Wave tile 32(M) x 64(N).
// ---------------------------------------------------------------------------
__global__ __launch_bounds__(256) void proj_gemm(
    const ushort* __restrict__ o,      // (8192, 512) bf16
    const ushort* __restrict__ wb,     // (512, 512) bf16
    const float* __restrict__ bias,    // (512,) f32
    float* __restrict__ out)           // (8192, 512) f32
{
    const int w_id = threadIdx.x >> 6;
    const int lane = threadIdx.x & 63;
    const int lr = lane & 15, quad = lane >> 4;
    const int m0 = blockIdx.x * 128 + w_id * 32;
    const int n0 = blockIdx.y * 64;

    floatx4 acc[2][4] = {};
    const ushort* orow0 = o + (size_t)(m0 + lr) * 512 + quad * 8;
    const ushort* orow1 = o + (size_t)(m0 + 16 + lr) * 512 + quad * 8;
    for (int kk = 0; kk < 512; kk += 32) {
        short8 a0 = *(const short8*)(orow0 + kk);
        short8 a1 = *(const short8*)(orow1 + kk);
#pragma unroll
        for (int nt = 0; nt < 4; ++nt) {
            short8 b = *(const short8*)(wb + (size_t)(n0 + nt * 16 + lr) * 512 + kk + quad * 8);
            acc[0][nt] = MFMA(a0, b, acc[0][nt]);
            acc[1][nt] = MFMA(a1, b, acc[1][nt]);
        }
    }
#pragma unroll
    for (int mt = 0; mt < 2; ++mt)
#pragma unroll
        for (int nt = 0; nt < 4; ++nt) {
            const int n = n0 + nt * 16 + lr;
            const float bv = bias[n];
#pragma unroll
            for (int r = 0; r < 4; ++r)
                out[(size_t)(m0 + mt * 16 + quad * 4 + r) * 512 + n] = acc[mt][nt][r] + bv;
        }
}

extern "C" void kernel_launch(void* const* d_in, const int* in_sizes, int n_in,
                              void* d_out, int out_size, void* d_ws, size_t ws_size,
                              hipStream_t stream)
{
    const float* x      = (const float*)d_in[0];
    const float* qkv_w  = (const float*)d_in[1];
    const float* qkv_b  = (const float*)d_in[2];
    const float* proj_w = (const float*)d_in[3];
    const float* proj_b = (const float*)d_in[4];
    float* out = (float*)d_out;

    const size_t MB = (size_t)1 << 20;
    ushort* base = (ushort*)d_ws;
    int G;
    ushort *xb, *o, *wb, *pwb, *q, *k, *vt;
    if (ws_size >= 34 * MB) {
        // G=8: single group -> o aliases xb (xb dead before flash runs)
        G = 8;
        xb = base; o = base;                 // 8 MiB shared
        wb  = base + 4194304;                // 1.5 MiB
        pwb = wb + 786432;                   // 0.5 MiB
        q   = pwb + 262144;
        k   = q + (size_t)G * 524288;
        vt  = k + (size_t)G * 524288;
    } else {
        G = (ws_size >= 30 * MB) ? 4 : (ws_size >= 24 * MB) ? 2 : 1;
        xb  = base;
        o   = base + 4194304;
        wb  = o + 4194304;
        pwb = wb + 786432;
        q   = pwb + 262144;
        k   = q + (size_t)G * 524288;
        vt  = k + (size_t)G * 524288;
    }

    // RoPE LUT in the head of d_out (1 MB) — dead before proj writes.
    float2* lut = (float2*)d_out;
    build_rope<<<512, 256, 0, stream>>>(lut);

    conv_bf16<<<2048, 256, 0, stream>>>(x, xb, 524288);
    conv_bf16<<<384, 256, 0, stream>>>(qkv_w, wb, 98304);
    conv_bf16<<<128, 256, 0, stream>>>(proj_w, pwb, 32768);

    for (int h0 = 0; h0 < 8; h0 += G) {
        qkv_rope<<<dim3(64, 3 * G), 256, 0, stream>>>(xb, wb, qkv_b, lut, q, k, vt, G, h0);
        flash_attn<0><<<128 * 2 * G, 256, 0, stream>>>(q, k, vt, o, G, h0);
        // Diagnostics: dead output into q (q is dead after flash<0> reads it;
        // next kernel_launch iteration rewrites q via qkv_rope).
        flash_attn<1><<<128 * 2 * G, 256, 0, stream>>>(q, k, vt, q, G, h0);
        flash_attn<2><<<128 * 2 * G, 256, 0, stream>>>(q, k, vt, q, G, h0);
    }
    proj_gemm<<<dim3(64, 8), 256, 0, stream>>>(o, pwb, proj_b, out);
}

// Round 8
// 278.297 us; speedup vs baseline: 3.5159x; 3.5159x over previous
//
#include <hip/hip_runtime.h>
#include <hip/hip_bf16.h>

// B=2, L=4096, C=512, H=8, hd=64. f32 in/out; bf16 MFMA compute.
// v15 (resubmit; r7 was an infra flake -- audited for OOB/hangs, none).
// Ablation-driven (r6): compute-only arm = 110us/unit at 79% VALUBusy
// (OCML exp2f is fat); real K AND V loads were 16-segment x 64B gathers
// (row stride 128B). Fixes: (a) FRAGMENT-PACKED K/V in memory -- qkv_rope
// stores exactly the per-lane MFMA fragments (K: [c][t][c2][lane][8],
// V: [c][dt][lane][8]) so every flash ldK/ldV is a contiguous 1KB
// wave-load; scatter moves to the write-once side (8MB) off the 128x-read
// side (1GB). (b) raw v_exp_f32 (args bounded, OCML fixup dead weight).
// Structure otherwise v12: 4 kh-quarter waves per 32-query block, register
// PV via 16x16x16 MFMA, K double-buffered, V single-buffered.

typedef __attribute__((ext_vector_type(8))) short short8;    // 8 bf16
typedef __attribute__((ext_vector_type(4))) short short4v;   // 4 bf16
typedef __attribute__((ext_vector_type(4))) float floatx4;   // MFMA C/D

#define MFMA(a, b, c)   __builtin_amdgcn_mfma_f32_16x16x32_bf16((a), (b), (c), 0, 0, 0)
#define MFMA16(a, b, c) __builtin_amdgcn_mfma_f32_16x16x16bf16_1k((a), (b), (c), 0, 0, 0)

__device__ __forceinline__ float fast_exp2(float x) {
#if __has_builtin(__builtin_amdgcn_exp2f)
    return __builtin_amdgcn_exp2f(x);
#else
    float r; asm("v_exp_f32 %0, %1" : "=v"(r) : "v"(x)); return r;
#endif
}

__device__ __forceinline__ unsigned short f2bf(float f) {
    unsigned int u = __builtin_bit_cast(unsigned int, f);
    return (unsigned short)((u + 0x7fffu + ((u >> 16) & 1u)) >> 16);  // RTNE
}
__device__ __forceinline__ unsigned int pack2(float lo, float hi) {
    __hip_bfloat162 h = __float22bfloat162_rn(make_float2(lo, hi));  // 1 instr
    unsigned int r;
    __builtin_memcpy(&r, &h, 4);
    return r;
}

__global__ __launch_bounds__(256) void conv_bf16(
    const float* __restrict__ src, ushort* __restrict__ dst, int n8)
{
    int i = blockIdx.x * blockDim.x + threadIdx.x;
    if (i >= n8) return;
    const float4* s = (const float4*)src + (size_t)i * 2;
    float4 a = s[0], b = s[1];
    uint4 r = { pack2(a.x, a.y), pack2(a.z, a.w), pack2(b.x, b.y), pack2(b.z, b.w) };
    *(uint4*)(dst + (size_t)i * 8) = r;
}

// RoPE LUT: lut[pos*32+j] = {cos, sin}(pos * 10000^(-j/32))
__global__ __launch_bounds__(256) void build_rope(float2* __restrict__ lut) {
    int i = blockIdx.x * 256 + threadIdx.x;   // 131072 entries
    int pos = i >> 5, j = i & 31;
    float invf = exp2f(-0.41524101186f * (float)j);
    float s, c;
    sincosf((float)pos * invf, &s, &c);
    lut[i] = make_float2(c, s);
}

// ---------------------------------------------------------------------------
// qkv = xb @ wb.T + b for G heads from h0; RoPE q,k (LUT); q pre-scaled by
// 0.125*log2e (flash uses exp2). q row-major. k FRAGMENT-PACKED:
// idx = c*2048 + t*1024 + c2*512 + quad*128 + lr*8 + e  for
// K[key=c*32+t*16+lr][d=c2*32+quad*8+e]. v FRAGMENT-PACKED (via LDS tile):
// idx = c*2048 + dt*512 + lane*8 + e for V[d=dt*16+(lane&15)]
// [key=c*32+(e>>2)*16+(lane>>4)*4+(e&3)]. Wave tile 32(M) x 64(N).
// ---------------------------------------------------------------------------
__global__ __launch_bounds__(256) void qkv_rope(
    const ushort* __restrict__ xb,    // (8192, 512) bf16
    const ushort* __restrict__ wb,    // (1536, 512) bf16
    const float* __restrict__ bias,   // (1536,) f32
    const float2* __restrict__ lut,   // (4096, 32)
    ushort* __restrict__ q, ushort* __restrict__ k, ushort* __restrict__ vt,
    int G, int h0)
{
    __shared__ __align__(16) ushort vtile[64][136];   // 17408 B (sec==2 only)
    const int w_id = threadIdx.x >> 6;
    const int lane = threadIdx.x & 63;
    const int lr = lane & 15, quad = lane >> 4;
    const int m0 = blockIdx.x * 128 + w_id * 32;
    const int sec = blockIdx.y / G, hl = blockIdx.y % G;
    const int wc0 = sec * 512 + (h0 + hl) * 64;

    floatx4 acc[2][4] = {};
    const ushort* xrow0 = xb + (size_t)(m0 + lr) * 512 + quad * 8;
    const ushort* xrow1 = xb + (size_t)(m0 + 16 + lr) * 512 + quad * 8;
    for (int kk = 0; kk < 512; kk += 32) {
        short8 a0 = *(const short8*)(xrow0 + kk);
        short8 a1 = *(const short8*)(xrow1 + kk);
#pragma unroll
        for (int nt = 0; nt < 4; ++nt) {
            short8 b = *(const short8*)(wb + (size_t)(wc0 + nt * 16 + lr) * 512 + kk + quad * 8);
            acc[0][nt] = MFMA(a0, b, acc[0][nt]);
            acc[1][nt] = MFMA(a1, b, acc[1][nt]);
        }
    }

    if (sec < 2) {
#pragma unroll
        for (int mt = 0; mt < 2; ++mt)
#pragma unroll
            for (int nt = 0; nt < 4; ++nt) {
                const int d = nt * 16 + lr;
                const float bv = bias[wc0 + d];
#pragma unroll
                for (int r = 0; r < 4; ++r) {
                    const int row = m0 + mt * 16 + quad * 4 + r;
                    const int b_ = row >> 12;
                    const int pos = row & 4095;
                    float val = acc[mt][nt][r] + bv;
                    const size_t bhl = (size_t)(b_ * G + hl);
                    float partner = __shfl_xor(val, 1);
                    float2 cs = lut[(pos << 5) | (d & 31)];
                    float rh = (d & 1) ? partner : -partner;   // rotate_half
                    float rv = val * cs.x + rh * cs.y;
                    if (sec == 0) {
                        rv *= 0.18033688011112042f;            // 0.125*log2(e)
                        q[(bhl * 4096 + pos) * 64 + d] = f2bf(rv);
                    } else {
                        // fragment-packed K
                        const int idx = (pos >> 5) * 2048 + ((pos >> 4) & 1) * 1024
                                      + (d >> 5) * 512 + ((d >> 3) & 3) * 128
                                      + (pos & 15) * 8 + (d & 7);
                        k[bhl * 262144 + idx] = f2bf(rv);
                    }
                }
            }
    } else {
        // v: stage bf16 tile (64 d x 128 pos) in LDS; emit fragment-packed,
        // 1KB-coalesced stores.
#pragma unroll
        for (int mt = 0; mt < 2; ++mt)
#pragma unroll
            for (int nt = 0; nt < 4; ++nt) {
                const int d = nt * 16 + lr;
                const float bv = bias[wc0 + d];
                short4v v4;
#pragma unroll
                for (int r = 0; r < 4; ++r)
                    v4[r] = (short)f2bf(acc[mt][nt][r] + bv);
                *(short4v*)&vtile[d][w_id * 32 + mt * 16 + quad * 4] = v4;
            }
        __syncthreads();
        const int m0b = blockIdx.x * 128;
        const int bb = m0b >> 12;
        const int pos0 = m0b & 4095;
        const size_t bhl = (size_t)(bb * G + hl);
        const int dt = w_id;                  // wave handles d-tile dt
        ushort* vb = vt + bhl * 262144 + dt * 512 + lane * 8;
#pragma unroll
        for (int j = 0; j < 4; ++j) {         // 4 chunks in this 128-pos tile
            const int col = j * 32 + quad * 4;
            short4v a = *(const short4v*)&vtile[dt * 16 + lr][col];        // t=0
            short4v b = *(const short4v*)&vtile[dt * 16 + lr][col + 16];   // t=1
            short8 vv = __builtin_shufflevector(a, b, 0, 1, 2, 3, 4, 5, 6, 7);
            *(short8*)(vb + ((pos0 >> 5) + j) * 2048) = vv;
        }
    }
}

// ---------------------------------------------------------------------------
// Flash v15. Block = 4 waves = 4 kh-quarters of ONE 32-query group; each
// wave covers 1024 keys in 32-key chunks, no-max softmax (raw v_exp_f32;
// log2e folded into q). K/V fragment-packed: every ldK/ldV is a contiguous
// 1KB wave-load. Per chunk: ldV(c) ; ldK(c+1) [reg dbuf] ; per (t,nn):
// qk (2 x32-MFMA) -> exp2 -> pack -> pv (4 x16-MFMA) in registers.
// 4-way serial merge of (O,l) in one LDS buffer. bhl = blockIdx.x % 2G.
// ---------------------------------------------------------------------------
__global__ __launch_bounds__(256, 3) void flash_attn(
    const ushort* __restrict__ q, const ushort* __restrict__ k,
    const ushort* __restrict__ vt, ushort* __restrict__ o,
    int G, int h0)
{
    __shared__ __align__(16) float mb[65][33];   // 8580 B merge buffer
    const int kh = threadIdx.x >> 6;             // wave = kh quarter
    const int lane = threadIdx.x & 63;
    const int lr = lane & 15, quad = lane >> 4;
    const int nbh = 2 * G;
    const int bhl = blockIdx.x % nbh;
    const int qtile = blockIdx.x / nbh;
    const int b_ = bhl / G, hl = bhl % G;
    const int q0 = qtile * 32;

    const ushort* qp = q + (size_t)bhl * 262144;
    ushort* op = o + (size_t)b_ * 4096 * 512 + (size_t)(h0 + hl) * 64;
    // fragment-packed bases for this kh quarter (chunks kh*32 ..)
    const ushort* kpw = k + (size_t)bhl * 262144 + kh * 65536 + lane * 8;
    const ushort* vpw = vt + (size_t)bhl * 262144 + kh * 65536 + lane * 8;

    // Q^T B-frags (q pre-scaled 0.125*log2e): qf[nn][c] = B[k=32c..][n=16nn+lr]
    short8 qf[2][2];
#pragma unroll
    for (int nn = 0; nn < 2; ++nn) {
        const ushort* qb = qp + (size_t)(q0 + 16 * nn + lr) * 64 + quad * 8;
        qf[nn][0] = *(const short8*)qb;
        qf[nn][1] = *(const short8*)(qb + 32);
    }

    floatx4 oacc[4][2] = {};   // [d-tile][n-tile]
    float lsum[2] = {0.f, 0.f};
    short8 ka0[2][2], ka1[2][2];
    short8 va[4];              // [d-tile]: low 4 = t0 frag, high 4 = t1 frag

    auto ldK = [&](int c, short8 (&ka)[2][2]) {
        const ushort* kb = kpw + c * 2048;
        ka[0][0] = *(const short8*)(kb);
        ka[0][1] = *(const short8*)(kb + 512);
        ka[1][0] = *(const short8*)(kb + 1024);
        ka[1][1] = *(const short8*)(kb + 1536);
    };
    auto ldV = [&](int c) {
        const ushort* vb = vpw + c * 2048;
#pragma unroll
        for (int dt = 0; dt < 4; ++dt)
            va[dt] = *(const short8*)(vb + dt * 512);
    };
    auto process = [&](short8 (&ka)[2][2]) {
#pragma unroll
        for (int t = 0; t < 2; ++t) {
#pragma unroll
            for (int nn = 0; nn < 2; ++nn) {
                floatx4 s = {};
                s = MFMA(ka[t][0], qf[nn][0], s);
                s = MFMA(ka[t][1], qf[nn][1], s);
                float p0 = fast_exp2(s[0]), p1 = fast_exp2(s[1]);
                float p2 = fast_exp2(s[2]), p3 = fast_exp2(s[3]);
                lsum[nn] += (p0 + p1) + (p2 + p3);
                uint2 u = { pack2(p0, p1), pack2(p2, p3) };
                short4v pf = __builtin_bit_cast(short4v, u);
#pragma unroll
                for (int dt = 0; dt < 4; ++dt) {
                    short4v vf = (t == 0)
                        ? __builtin_shufflevector(va[dt], va[dt], 0, 1, 2, 3)
                        : __builtin_shufflevector(va[dt], va[dt], 4, 5, 6, 7);
                    oacc[dt][nn] = MFMA16(vf, pf, oacc[dt][nn]);
                }
            }
        }
    };

    ldK(0, ka0);
    for (int it = 0; it < 30; it += 2) {
        ldV(it);
        ldK(it + 1, ka1);
        process(ka0);
        ldV(it + 1);
        ldK(it + 2, ka0);
        process(ka1);
    }
    ldV(30); ldK(31, ka1); process(ka0);   // chunk 30
    ldV(31); process(ka1);                 // chunk 31

    // l across quads (queries in lr; quads hold disjoint keys)
    lsum[0] += __shfl_xor(lsum[0], 16); lsum[0] += __shfl_xor(lsum[0], 32);
    lsum[1] += __shfl_xor(lsum[1], 16); lsum[1] += __shfl_xor(lsum[1], 32);

    // 4-way serial merge: kh=3 writes, kh=2,1 accumulate, kh=0 finalizes.
    __syncthreads();
    if (kh == 3) {
#pragma unroll
        for (int dt = 0; dt < 4; ++dt)
#pragma unroll
            for (int nn = 0; nn < 2; ++nn)
#pragma unroll
                for (int r = 0; r < 4; ++r)
                    mb[16 * dt + 4 * quad + r][16 * nn + lr] = oacc[dt][nn][r];
        if (quad == 0) {
            mb[64][lr] = lsum[0];
            mb[64][16 + lr] = lsum[1];
        }
    }
    __syncthreads();
    if (kh == 2) {
#pragma unroll
        for (int dt = 0; dt < 4; ++dt)
#pragma unroll
            for (int nn = 0; nn < 2; ++nn)
#pragma unroll
                for (int r = 0; r < 4; ++r)
                    mb[16 * dt + 4 * quad + r][16 * nn + lr] += oacc[dt][nn][r];
        if (quad == 0) {
            mb[64][lr] += lsum[0];
            mb[64][16 + lr] += lsum[1];
        }
    }
    __syncthreads();
    if (kh == 1) {
#pragma unroll
        for (int dt = 0; dt < 4; ++dt)
#pragma unroll
            for (int nn = 0; nn < 2; ++nn)
#pragma unroll
                for (int r = 0; r < 4; ++r)
                    mb[16 * dt + 4 * quad + r][16 * nn + lr] += oacc[dt][nn][r];
        if (quad == 0) {
            mb[64][lr] += lsum[0];
            mb[64][16 + lr] += lsum[1];
        }
    }
    __syncthreads();
    if (kh == 0) {
        float inv0 = 1.0f / (lsum[0] + mb[64][lr]);
        float inv1 = 1.0f / (lsum[1] + mb[64][16 + lr]);
#pragma unroll
        for (int dt = 0; dt < 4; ++dt)
#pragma unroll
            for (int nn = 0; nn < 2; ++nn) {
                float inv = nn ? inv1 : inv0;
                float v0 = (oacc[dt][nn][0] + mb[16 * dt + 4 * quad + 0][16 * nn + lr]) * inv;
                float v1 = (oacc[dt][nn][1] + mb[16 * dt + 4 * quad + 1][16 * nn + lr]) * inv;
                float v2 = (oacc[dt][nn][2] + mb[16 * dt + 4 * quad + 2][16 * nn + lr]) * inv;
                float v3 = (oacc[dt][nn][3] + mb[16 * dt + 4 * quad + 3][16 * nn + lr]) * inv;
                uint2 u = { pack2(v0, v1), pack2(v2, v3) };
                *(uint2*)(op + (size_t)(q0 + 16 * nn + lr) * 512 + 16 * dt + 4 * quad) = u;
            }
    }
}

// ---------------------------------------------------------------------------
// out(f32) = o(bf16) @ wb.T + proj_b. Wave tile 32(M) x 64(N).
// ---------------------------------------------------------------------------
__global__ __launch_bounds__(256) void proj_gemm(
    const ushort* __restrict__ o,      // (8192, 512) bf16
    const ushort* __restrict__ wb,     // (512, 512) bf16
    const float* __restrict__ bias,    // (512,) f32
    float* __restrict__ out)           // (8192, 512) f32
{
    const int w_id = threadIdx.x >> 6;
    const int lane = threadIdx.x & 63;
    const int lr = lane & 15, quad = lane >> 4;
    const int m0 = blockIdx.x * 128 + w_id * 32;
    const int n0 = blockIdx.y * 64;

    floatx4 acc[2][4] = {};
    const ushort* orow0 = o + (size_t)(m0 + lr) * 512 + quad * 8;
    const ushort* orow1 = o + (size_t)(m0 + 16 + lr) * 512 + quad * 8;
    for (int kk = 0; kk < 512; kk += 32) {
        short8 a0 = *(const short8*)(orow0 + kk);
        short8 a1 = *(const short8*)(orow1 + kk);
#pragma unroll
        for (int nt = 0; nt < 4; ++nt) {
            short8 b = *(const short8*)(wb + (size_t)(n0 + nt * 16 + lr) * 512 + kk + quad * 8);
            acc[0][nt] = MFMA(a0, b, acc[0][nt]);
            acc[1][nt] = MFMA(a1, b, acc[1][nt]);
        }
    }
#pragma unroll
    for (int mt = 0; mt < 2; ++mt)
#pragma unroll
        for (int nt = 0; nt < 4; ++nt) {
            const int n = n0 + nt * 16 + lr;
            const float bv = bias[n];
#pragma unroll
            for (int r = 0; r < 4; ++r)
                out[(size_t)(m0 + mt * 16 + quad * 4 + r) * 512 + n] = acc[mt][nt][r] + bv;
        }
}

extern "C" void kernel_launch(void* const* d_in, const int* in_sizes, int n_in,
                              void* d_out, int out_size, void* d_ws, size_t ws_size,
                              hipStream_t stream)
{
    const float* x      = (const float*)d_in[0];
    const float* qkv_w  = (const float*)d_in[1];
    const float* qkv_b  = (const float*)d_in[2];
    const float* proj_w = (const float*)d_in[3];
    const float* proj_b = (const float*)d_in[4];
    float* out = (float*)d_out;

    const size_t MB = (size_t)1 << 20;
    ushort* base = (ushort*)d_ws;
    int G;
    ushort *xb, *o, *wb, *pwb, *q, *k, *vt;
    if (ws_size >= 34 * MB) {
        // G=8: single group -> o aliases xb (xb dead before flash runs)
        G = 8;
        xb = base; o = base;                 // 8 MiB shared
        wb  = base + 4194304;                // 1.5 MiB
        pwb = wb + 786432;                   // 0.5 MiB
        q   = pwb + 262144;
        k   = q + (size_t)G * 524288;
        vt  = k + (size_t)G * 524288;
    } else {
        G = (ws_size >= 30 * MB) ? 4 : (ws_size >= 24 * MB) ? 2 : 1;
        xb  = base;
        o   = base + 4194304;
        wb  = o + 4194304;
        pwb = wb + 786432;
        q   = pwb + 262144;
        k   = q + (size_t)G * 524288;
        vt  = k + (size_t)G * 524288;
    }

    // RoPE LUT in the head of d_out (1 MB) — dead before proj writes.
    float2* lut = (float2*)d_out;
    build_rope<<<512, 256, 0, stream>>>(lut);

    conv_bf16<<<2048, 256, 0, stream>>>(x, xb, 524288);
    conv_bf16<<<384, 256, 0, stream>>>(qkv_w, wb, 98304);
    conv_bf16<<<128, 256, 0, stream>>>(proj_w, pwb, 32768);

    for (int h0 = 0; h0 < 8; h0 += G) {
        qkv_rope<<<dim3(64, 3 * G), 256, 0, stream>>>(xb, wb, qkv_b, lut, q, k, vt, G, h0);
        flash_attn<<<128 * 2 * G, 256, 0, stream>>>(q, k, vt, o, G, h0);
    }
    proj_gemm<<<dim3(64, 8), 256, 0, stream>>>(o, pwb, proj_b, out);
}

// Round 9
// 219.908 us; speedup vs baseline: 4.4494x; 1.2655x over previous
//
#include <hip/hip_runtime.h>
#include <hip/hip_bf16.h>

// B=2, L=4096, C=512, H=8, hd=64. f32 in/out; bf16 MFMA compute.
// v16: v15 (flash 100us via fragment-packed K/V + raw v_exp_f32) + the same
// medicine for the GEMMs. qkv_rope/proj_gemm loaded A and B as 16-row x 64B
// row-stride gathers (96 TA segments per k-step vs 8 MFMA). Now ALL GEMM
// operands are FRAGMENT-PACKED at write-once time:
//   pidx(row,col) = (row>>4)*8192 + (col>>5)*512
//                 + ((row&15) + 16*((col>>3)&3))*8 + (col&7)
// conv_pack writes xb/wb/pwb packed (coalesced f32 reads, scattered 16B
// stores -- paid once on 10MB). flash writes o packed at zero cost (same
// 8B stores, permuted address). Every GEMM k-step operand load is then a
// contiguous 1KB wave-load: base + kk*512 + lane*8.

typedef __attribute__((ext_vector_type(8))) short short8;    // 8 bf16
typedef __attribute__((ext_vector_type(4))) short short4v;   // 4 bf16
typedef __attribute__((ext_vector_type(4))) float floatx4;   // MFMA C/D

#define MFMA(a, b, c)   __builtin_amdgcn_mfma_f32_16x16x32_bf16((a), (b), (c), 0, 0, 0)
#define MFMA16(a, b, c) __builtin_amdgcn_mfma_f32_16x16x16bf16_1k((a), (b), (c), 0, 0, 0)

__device__ __forceinline__ float fast_exp2(float x) {
#if __has_builtin(__builtin_amdgcn_exp2f)
    return __builtin_amdgcn_exp2f(x);
#else
    float r; asm("v_exp_f32 %0, %1" : "=v"(r) : "v"(x)); return r;
#endif
}

__device__ __forceinline__ unsigned short f2bf(float f) {
    unsigned int u = __builtin_bit_cast(unsigned int, f);
    return (unsigned short)((u + 0x7fffu + ((u >> 16) & 1u)) >> 16);  // RTNE
}
__device__ __forceinline__ unsigned int pack2(float lo, float hi) {
    __hip_bfloat162 h = __float22bfloat162_rn(make_float2(lo, hi));  // 1 instr
    unsigned int r;
    __builtin_memcpy(&r, &h, 4);
    return r;
}

// ---------------------------------------------------------------------------
// f32 (rows, 512) row-major -> bf16 FRAGMENT-PACKED (A/B operand layout).
// Thread i: row = i>>6, col0 = (i&63)*8. Coalesced 32B f32 reads; one 16B
// store at the packed address (scattered across the wave -- write-once).
// ---------------------------------------------------------------------------
__global__ __launch_bounds__(256) void conv_pack(
    const float* __restrict__ src, ushort* __restrict__ dst, int n8)
{
    int i = blockIdx.x * blockDim.x + threadIdx.x;
    if (i >= n8) return;
    const int row = i >> 6, col0 = (i & 63) * 8;
    const float4* s = (const float4*)(src + (size_t)row * 512 + col0);
    float4 a = s[0], b = s[1];
    uint4 r = { pack2(a.x, a.y), pack2(a.z, a.w), pack2(b.x, b.y), pack2(b.z, b.w) };
    const int l = (row & 15) + 16 * ((col0 >> 3) & 3);
    const size_t off = (size_t)(row >> 4) * 8192 + (size_t)(col0 >> 5) * 512 + l * 8;
    *(uint4*)(dst + off) = r;
}

// RoPE LUT: lut[pos*32+j] = {cos, sin}(pos * 10000^(-j/32))
__global__ __launch_bounds__(256) void build_rope(float2* __restrict__ lut) {
    int i = blockIdx.x * 256 + threadIdx.x;   // 131072 entries
    int pos = i >> 5, j = i & 31;
    float invf = exp2f(-0.41524101186f * (float)j);
    float s, c;
    sincosf((float)pos * invf, &s, &c);
    lut[i] = make_float2(c, s);
}

// ---------------------------------------------------------------------------
// qkv = xb @ wb.T + b for G heads from h0; RoPE q,k (LUT); q pre-scaled by
// 0.125*log2e. xb/wb fragment-packed -> every k-step operand load is a
// contiguous 1KB wave-load. q row-major. k FRAGMENT-PACKED (flash layout):
// idx = c*2048 + t*1024 + c2*512 + quad*128 + lr*8 + e. v FRAGMENT-PACKED
// via LDS tile: idx = c*2048 + dt*512 + lane*8 + e. Wave 32(M) x 64(N).
// ---------------------------------------------------------------------------
__global__ __launch_bounds__(256) void qkv_rope(
    const ushort* __restrict__ xb,    // packed (8192, 512) bf16
    const ushort* __restrict__ wb,    // packed (1536, 512) bf16
    const float* __restrict__ bias,   // (1536,) f32
    const float2* __restrict__ lut,   // (4096, 32)
    ushort* __restrict__ q, ushort* __restrict__ k, ushort* __restrict__ vt,
    int G, int h0)
{
    __shared__ __align__(16) ushort vtile[64][136];   // 17408 B (sec==2 only)
    const int w_id = threadIdx.x >> 6;
    const int lane = threadIdx.x & 63;
    const int lr = lane & 15, quad = lane >> 4;
    const int m0 = blockIdx.x * 128 + w_id * 32;
    const int sec = blockIdx.y / G, hl = blockIdx.y % G;
    const int wc0 = sec * 512 + (h0 + hl) * 64;

    floatx4 acc[2][4] = {};
    const ushort* xa = xb + (size_t)(m0 >> 4) * 8192 + lane * 8;
    const ushort* wbase = wb + (size_t)(wc0 >> 4) * 8192 + lane * 8;
    for (int kk = 0; kk < 16; ++kk) {
        short8 a0 = *(const short8*)(xa + kk * 512);
        short8 a1 = *(const short8*)(xa + 8192 + kk * 512);
#pragma unroll
        for (int nt = 0; nt < 4; ++nt) {
            short8 b = *(const short8*)(wbase + (size_t)nt * 8192 + kk * 512);
            acc[0][nt] = MFMA(a0, b, acc[0][nt]);
            acc[1][nt] = MFMA(a1, b, acc[1][nt]);
        }
    }

    if (sec < 2) {
#pragma unroll
        for (int mt = 0; mt < 2; ++mt)
#pragma unroll
            for (int nt = 0; nt < 4; ++nt) {
                const int d = nt * 16 + lr;
                const float bv = bias[wc0 + d];
#pragma unroll
                for (int r = 0; r < 4; ++r) {
                    const int row = m0 + mt * 16 + quad * 4 + r;
                    const int b_ = row >> 12;
                    const int pos = row & 4095;
                    float val = acc[mt][nt][r] + bv;
                    const size_t bhl = (size_t)(b_ * G + hl);
                    float partner = __shfl_xor(val, 1);
                    float2 cs = lut[(pos << 5) | (d & 31)];
                    float rh = (d & 1) ? partner : -partner;   // rotate_half
                    float rv = val * cs.x + rh * cs.y;
                    if (sec == 0) {
                        rv *= 0.18033688011112042f;            // 0.125*log2(e)
                        q[(bhl * 4096 + pos) * 64 + d] = f2bf(rv);
                    } else {
                        // fragment-packed K (flash layout)
                        const int idx = (pos >> 5) * 2048 + ((pos >> 4) & 1) * 1024
                                      + (d >> 5) * 512 + ((d >> 3) & 3) * 128
                                      + (pos & 15) * 8 + (d & 7);
                        k[bhl * 262144 + idx] = f2bf(rv);
                    }
                }
            }
    } else {
        // v: stage bf16 tile (64 d x 128 pos) in LDS; emit fragment-packed,
        // 1KB-coalesced stores.
#pragma unroll
        for (int mt = 0; mt < 2; ++mt)
#pragma unroll
            for (int nt = 0; nt < 4; ++nt) {
                const int d = nt * 16 + lr;
                const float bv = bias[wc0 + d];
                short4v v4;
#pragma unroll
                for (int r = 0; r < 4; ++r)
                    v4[r] = (short)f2bf(acc[mt][nt][r] + bv);
                *(short4v*)&vtile[d][w_id * 32 + mt * 16 + quad * 4] = v4;
            }
        __syncthreads();
        const int m0b = blockIdx.x * 128;
        const int bb = m0b >> 12;
        const int pos0 = m0b & 4095;
        const size_t bhl = (size_t)(bb * G + hl);
        const int dt = w_id;                  // wave handles d-tile dt
        ushort* vb = vt + bhl * 262144 + dt * 512 + lane * 8;
#pragma unroll
        for (int j = 0; j < 4; ++j) {         // 4 chunks in this 128-pos tile
            const int col = j * 32 + quad * 4;
            short4v a = *(const short4v*)&vtile[dt * 16 + lr][col];        // t=0
            short4v b = *(const short4v*)&vtile[dt * 16 + lr][col + 16];   // t=1
            short8 vv = __builtin_shufflevector(a, b, 0, 1, 2, 3, 4, 5, 6, 7);
            *(short8*)(vb + ((pos0 >> 5) + j) * 2048) = vv;
        }
    }
}

// ---------------------------------------------------------------------------
// Flash v16. Block = 4 waves = 4 kh-quarters of ONE 32-query group; each
// wave covers 1024 keys in 32-key chunks, no-max softmax (raw v_exp_f32;
// log2e folded into q). K/V fragment-packed: every ldK/ldV is a contiguous
// 1KB wave-load. Output o written FRAGMENT-PACKED (proj's A operand) at
// zero cost. 4-way serial merge of (O,l) in one LDS buffer.
// ---------------------------------------------------------------------------
__global__ __launch_bounds__(256, 3) void flash_attn(
    const ushort* __restrict__ q, const ushort* __restrict__ k,
    const ushort* __restrict__ vt, ushort* __restrict__ o,
    int G, int h0)
{
    __shared__ __align__(16) float mb[65][33];   // 8580 B merge buffer
    const int kh = threadIdx.x >> 6;             // wave = kh quarter
    const int lane = threadIdx.x & 63;
    const int lr = lane & 15, quad = lane >> 4;
    const int nbh = 2 * G;
    const int bhl = blockIdx.x % nbh;
    const int qtile = blockIdx.x / nbh;
    const int b_ = bhl / G, hl = bhl % G;
    const int q0 = qtile * 32;

    const ushort* qp = q + (size_t)bhl * 262144;
    // fragment-packed o base: 16-row tile ((b_*4096+q0)>>4), head col block
    const int hcol = (h0 + hl) * 64;
    ushort* opp = o + (size_t)(((b_ << 12) + q0) >> 4) * 8192 + (hcol >> 5) * 512;
    // fragment-packed K/V bases for this kh quarter (chunks kh*32 ..)
    const ushort* kpw = k + (size_t)bhl * 262144 + kh * 65536 + lane * 8;
    const ushort* vpw = vt + (size_t)bhl * 262144 + kh * 65536 + lane * 8;

    // Q^T B-frags (q pre-scaled 0.125*log2e): qf[nn][c] = B[k=32c..][n=16nn+lr]
    short8 qf[2][2];
#pragma unroll
    for (int nn = 0; nn < 2; ++nn) {
        const ushort* qb = qp + (size_t)(q0 + 16 * nn + lr) * 64 + quad * 8;
        qf[nn][0] = *(const short8*)qb;
        qf[nn][1] = *(const short8*)(qb + 32);
    }

    floatx4 oacc[4][2] = {};   // [d-tile][n-tile]
    float lsum[2] = {0.f, 0.f};
    short8 ka0[2][2], ka1[2][2];
    short8 va[4];              // [d-tile]: low 4 = t0 frag, high 4 = t1 frag

    auto ldK = [&](int c, short8 (&ka)[2][2]) {
        const ushort* kb = kpw + c * 2048;
        ka[0][0] = *(const short8*)(kb);
        ka[0][1] = *(const short8*)(kb + 512);
        ka[1][0] = *(const short8*)(kb + 1024);
        ka[1][1] = *(const short8*)(kb + 1536);
    };
    auto ldV = [&](int c) {
        const ushort* vb = vpw + c * 2048;
#pragma unroll
        for (int dt = 0; dt < 4; ++dt)
            va[dt] = *(const short8*)(vb + dt * 512);
    };
    auto process = [&](short8 (&ka)[2][2]) {
#pragma unroll
        for (int t = 0; t < 2; ++t) {
#pragma unroll
            for (int nn = 0; nn < 2; ++nn) {
                floatx4 s = {};
                s = MFMA(ka[t][0], qf[nn][0], s);
                s = MFMA(ka[t][1], qf[nn][1], s);
                float p0 = fast_exp2(s[0]), p1 = fast_exp2(s[1]);
                float p2 = fast_exp2(s[2]), p3 = fast_exp2(s[3]);
                lsum[nn] += (p0 + p1) + (p2 + p3);
                uint2 u = { pack2(p0, p1), pack2(p2, p3) };
                short4v pf = __builtin_bit_cast(short4v, u);
#pragma unroll
                for (int dt = 0; dt < 4; ++dt) {
                    short4v vf = (t == 0)
                        ? __builtin_shufflevector(va[dt], va[dt], 0, 1, 2, 3)
                        : __builtin_shufflevector(va[dt], va[dt], 4, 5, 6, 7);
                    oacc[dt][nn] = MFMA16(vf, pf, oacc[dt][nn]);
                }
            }
        }
    };

    ldK(0, ka0);
    for (int it = 0; it < 30; it += 2) {
        ldV(it);
        ldK(it + 1, ka1);
        process(ka0);
        ldV(it + 1);
        ldK(it + 2, ka0);
        process(ka1);
    }
    ldV(30); ldK(31, ka1); process(ka0);   // chunk 30
    ldV(31); process(ka1);                 // chunk 31

    // l across quads (queries in lr; quads hold disjoint keys)
    lsum[0] += __shfl_xor(lsum[0], 16); lsum[0] += __shfl_xor(lsum[0], 32);
    lsum[1] += __shfl_xor(lsum[1], 16); lsum[1] += __shfl_xor(lsum[1], 32);

    // 4-way serial merge: kh=3 writes, kh=2,1 accumulate, kh=0 finalizes.
    __syncthreads();
    if (kh == 3) {
#pragma unroll
        for (int dt = 0; dt < 4; ++dt)
#pragma unroll
            for (int nn = 0; nn < 2; ++nn)
#pragma unroll
                for (int r = 0; r < 4; ++r)
                    mb[16 * dt + 4 * quad + r][16 * nn + lr] = oacc[dt][nn][r];
        if (quad == 0) {
            mb[64][lr] = lsum[0];
            mb[64][16 + lr] = lsum[1];
        }
    }
    __syncthreads();
    if (kh == 2) {
#pragma unroll
        for (int dt = 0; dt < 4; ++dt)
#pragma unroll
            for (int nn = 0; nn < 2; ++nn)
#pragma unroll
                for (int r = 0; r < 4; ++r)
                    mb[16 * dt + 4 * quad + r][16 * nn + lr] += oacc[dt][nn][r];
        if (quad == 0) {
            mb[64][lr] += lsum[0];
            mb[64][16 + lr] += lsum[1];
        }
    }
    __syncthreads();
    if (kh == 1) {
#pragma unroll
        for (int dt = 0; dt < 4; ++dt)
#pragma unroll
            for (int nn = 0; nn < 2; ++nn)
#pragma unroll
                for (int r = 0; r < 4; ++r)
                    mb[16 * dt + 4 * quad + r][16 * nn + lr] += oacc[dt][nn][r];
        if (quad == 0) {
            mb[64][lr] += lsum[0];
            mb[64][16 + lr] += lsum[1];
        }
    }
    __syncthreads();
    if (kh == 0) {
        float inv0 = 1.0f / (lsum[0] + mb[64][lr]);
        float inv1 = 1.0f / (lsum[1] + mb[64][16 + lr]);
#pragma unroll
        for (int dt = 0; dt < 4; ++dt)
#pragma unroll
            for (int nn = 0; nn < 2; ++nn) {
                float inv = nn ? inv1 : inv0;
                float v0 = (oacc[dt][nn][0] + mb[16 * dt + 4 * quad + 0][16 * nn + lr]) * inv;
                float v1 = (oacc[dt][nn][1] + mb[16 * dt + 4 * quad + 1][16 * nn + lr]) * inv;
                float v2 = (oacc[dt][nn][2] + mb[16 * dt + 4 * quad + 2][16 * nn + lr]) * inv;
                float v3 = (oacc[dt][nn][3] + mb[16 * dt + 4 * quad + 3][16 * nn + lr]) * inv;
                uint2 u = { pack2(v0, v1), pack2(v2, v3) };
                // fragment-packed o store (8B, same cost as row-major)
                const int cg = 16 * dt + 4 * quad;
                *(uint2*)(opp + (size_t)nn * 8192 + (cg >> 5) * 512
                          + (lr + 16 * ((cg >> 3) & 3)) * 8 + (cg & 7)) = u;
            }
    }
}

// ---------------------------------------------------------------------------
// out(f32) = o(bf16, packed) @ wb.T(packed) + proj_b. Wave 32(M) x 64(N).
// ---------------------------------------------------------------------------
__global__ __launch_bounds__(256) void proj_gemm(
    const ushort* __restrict__ o,      // packed (8192, 512) bf16
    const ushort* __restrict__ wb,     // packed (512, 512) bf16
    const float* __restrict__ bias,    // (512,) f32
    float* __restrict__ out)           // (8192, 512) f32
{
    const int w_id = threadIdx.x >> 6;
    const int lane = threadIdx.x & 63;
    const int lr = lane & 15, quad = lane >> 4;
    const int m0 = blockIdx.x * 128 + w_id * 32;
    const int n0 = blockIdx.y * 64;

    floatx4 acc[2][4] = {};
    const ushort* oa = o + (size_t)(m0 >> 4) * 8192 + lane * 8;
    const ushort* wbase = wb + (size_t)(n0 >> 4) * 8192 + lane * 8;
    for (int kk = 0; kk < 16; ++kk) {
        short8 a0 = *(const short8*)(oa + kk * 512);
        short8 a1 = *(const short8*)(oa + 8192 + kk * 512);
#pragma unroll
        for (int nt = 0; nt < 4; ++nt) {
            short8 b = *(const short8*)(wbase + (size_t)nt * 8192 + kk * 512);
            acc[0][nt] = MFMA(a0, b, acc[0][nt]);
            acc[1][nt] = MFMA(a1, b, acc[1][nt]);
        }
    }
#pragma unroll
    for (int mt = 0; mt < 2; ++mt)
#pragma unroll
        for (int nt = 0; nt < 4; ++nt) {
            const int n = n0 + nt * 16 + lr;
            const float bv = bias[n];
#pragma unroll
            for (int r = 0; r < 4; ++r)
                out[(size_t)(m0 + mt * 16 + quad * 4 + r) * 512 + n] = acc[mt][nt][r] + bv;
        }
}

extern "C" void kernel_launch(void* const* d_in, const int* in_sizes, int n_in,
                              void* d_out, int out_size, void* d_ws, size_t ws_size,
                              hipStream_t stream)
{
    const float* x      = (const float*)d_in[0];
    const float* qkv_w  = (const float*)d_in[1];
    const float* qkv_b  = (const float*)d_in[2];
    const float* proj_w = (const float*)d_in[3];
    const float* proj_b = (const float*)d_in[4];
    float* out = (float*)d_out;

    const size_t MB = (size_t)1 << 20;
    ushort* base = (ushort*)d_ws;
    int G;
    ushort *xb, *o, *wb, *pwb, *q, *k, *vt;
    if (ws_size >= 34 * MB) {
        // G=8: single group -> o aliases xb (xb dead before flash runs)
        G = 8;
        xb = base; o = base;                 // 8 MiB shared
        wb  = base + 4194304;                // 1.5 MiB
        pwb = wb + 786432;                   // 0.5 MiB
        q   = pwb + 262144;
        k   = q + (size_t)G * 524288;
        vt  = k + (size_t)G * 524288;
    } else {
        G = (ws_size >= 30 * MB) ? 4 : (ws_size >= 24 * MB) ? 2 : 1;
        xb  = base;
        o   = base + 4194304;
        wb  = o + 4194304;
        pwb = wb + 786432;
        q   = pwb + 262144;
        k   = q + (size_t)G * 524288;
        vt  = k + (size_t)G * 524288;
    }

    // RoPE LUT in the head of d_out (1 MB) — dead before proj writes.
    float2* lut = (float2*)d_out;
    build_rope<<<512, 256, 0, stream>>>(lut);

    conv_pack<<<2048, 256, 0, stream>>>(x, xb, 524288);
    conv_pack<<<384, 256, 0, stream>>>(qkv_w, wb, 98304);
    conv_pack<<<128, 256, 0, stream>>>(proj_w, pwb, 32768);

    for (int h0 = 0; h0 < 8; h0 += G) {
        qkv_rope<<<dim3(64, 3 * G), 256, 0, stream>>>(xb, wb, qkv_b, lut, q, k, vt, G, h0);
        flash_attn<<<128 * 2 * G, 256, 0, stream>>>(q, k, vt, o, G, h0);
    }
    proj_gemm<<<dim3(64, 8), 256, 0, stream>>>(o, pwb, proj_b, out);
}